// Round 4
// baseline (138.001 us; speedup 1.0000x reference)
//
#include <hip/hip_runtime.h>

// BCMSELoss: scalar = mean((out_full - tgt_full)^2) + sum(|floor(o_ang)|)/B
// cols 1,2 angular-wrapped, col 0 plain MSE. Memory-bound: 201 MB read.
//
// R1: grid-stride @16 VGPR -> latency-bound, 950 GB/s.
// R2: 3 f4-pairs/thread one-shot -> 4.5 TB/s.
// R3: 8 f4-pairs/thread, grid 3072 -> 5.2 TB/s combined (timed 38.8 us).
// R4: fuse the 1-block reduce into the main kernel (last-block-done via
//     device-scope counter) -> kill the 2nd launch + gap (~4-7 us).

constexpr int BLOCK = 256;
constexpr int F4T = 8;                      // float4-pairs per thread
constexpr int F4_PER_BLOCK = BLOCK * F4T;   // 2048

__device__ inline void elem(float oo, float tt, bool ang, float& sq, float& pen) {
    const float fl = floorf(oo);
    const float ow = oo - fl;                       // mod(o, 1.0)
    const float shift = (tt < ow) ? 1.0f : -1.0f;
    const float ts = (fabsf(ow - tt) > 0.5f) ? (tt + shift) : tt;
    const float da = ow - ts;
    const float dl = oo - tt;
    const float d = ang ? da : dl;
    sq = fmaf(d, d, sq);
    pen += ang ? fabsf(fl) : 0.0f;
}

__device__ inline void proc4(const float4 o, const float4 t, int im,
                             float& sq, float& pen) {
    // element e = 4*i + j; 4 == 1 (mod 3) so e%3 == (i+j)%3; im = i%3
    elem(o.x, t.x, im != 0, sq, pen);
    const int c1 = (im == 2) ? 0 : im + 1;
    elem(o.y, t.y, c1 != 0, sq, pen);
    const int c2 = (c1 == 2) ? 0 : c1 + 1;
    elem(o.z, t.z, c2 != 0, sq, pen);
    const int c3 = (c2 == 2) ? 0 : c2 + 1;
    elem(o.w, t.w, c3 != 0, sq, pen);
}

__global__ __launch_bounds__(BLOCK) void bcmse_fused(
    const float* __restrict__ outs,
    const float* __restrict__ tgts,
    long long n,                              // total elements = B*3
    unsigned long long* __restrict__ partials, // one packed float2 per block
    unsigned* __restrict__ counter,           // zeroed each launch
    float* __restrict__ out,
    double invN, double invB)
{
    const long long n4 = n >> 2;
    const long long base = (long long)blockIdx.x * F4_PER_BLOCK + threadIdx.x;

    const float4* __restrict__ o4 = reinterpret_cast<const float4*>(outs);
    const float4* __restrict__ t4 = reinterpret_cast<const float4*>(tgts);

    long long idx[F4T];
    bool g[F4T];
    #pragma unroll
    for (int k = 0; k < F4T; ++k) {
        const long long i = base + (long long)k * BLOCK;
        g[k] = i < n4;
        idx[k] = g[k] ? i : 0;
    }

    // issue all loads before any wait -> max MLP
    float4 ov[F4T], tv[F4T];
    #pragma unroll
    for (int k = 0; k < F4T; ++k) ov[k] = o4[idx[k]];
    #pragma unroll
    for (int k = 0; k < F4T; ++k) tv[k] = t4[idx[k]];

    // BLOCK=256, 256%3==1 -> i%3 advances by 1 per chunk
    int im = (int)(base % 3);

    float sq = 0.f, pen = 0.f;
    #pragma unroll
    for (int k = 0; k < F4T; ++k) {
        float s = 0.f, p = 0.f;
        proc4(ov[k], tv[k], im, s, p);
        if (g[k]) { sq += s; pen += p; }
        im = (im == 2) ? 0 : im + 1;
    }

    // scalar tail (n % 4 != 0) — never fires for n = 25165824
    if (blockIdx.x == 0 && threadIdx.x == 0) {
        for (long long e = n4 * 4; e < n; ++e) {
            elem(outs[e], tgts[e], (e % 3) != 0, sq, pen);
        }
    }

    // wave-64 reduce
    #pragma unroll
    for (int off = 32; off > 0; off >>= 1) {
        sq  += __shfl_down(sq,  off, 64);
        pen += __shfl_down(pen, off, 64);
    }

    __shared__ float s_sq[BLOCK / 64], s_pen[BLOCK / 64];
    __shared__ bool s_last;
    const int lane = threadIdx.x & 63;
    const int wave = threadIdx.x >> 6;
    if (lane == 0) { s_sq[wave] = sq; s_pen[wave] = pen; }
    __syncthreads();

    if (threadIdx.x == 0) {
        float bsq = 0.f, bpen = 0.f;
        #pragma unroll
        for (int w = 0; w < BLOCK / 64; ++w) { bsq += s_sq[w]; bpen += s_pen[w]; }
        union { float2 f; unsigned long long u; } pk;
        pk.f = make_float2(bsq, bpen);
        // agent-scope store: visible across XCD L2s once the release-add lands
        __hip_atomic_store(&partials[blockIdx.x], pk.u,
                           __ATOMIC_RELAXED, __HIP_MEMORY_SCOPE_AGENT);
        const unsigned prev = __hip_atomic_fetch_add(counter, 1u,
                           __ATOMIC_ACQ_REL, __HIP_MEMORY_SCOPE_AGENT);
        s_last = (prev == gridDim.x - 1);
    }
    __syncthreads();

    if (s_last) {
        // last block reduces all partials (fixed order per thread -> deterministic)
        double dsq = 0.0, dpen = 0.0;
        const int nb = (int)gridDim.x;
        for (int k = threadIdx.x; k < nb; k += BLOCK) {
            union { float2 f; unsigned long long u; } pk;
            pk.u = __hip_atomic_load(&partials[k],
                       __ATOMIC_RELAXED, __HIP_MEMORY_SCOPE_AGENT);
            dsq  += (double)pk.f.x;
            dpen += (double)pk.f.y;
        }
        #pragma unroll
        for (int off = 32; off > 0; off >>= 1) {
            dsq  += __shfl_down(dsq,  off, 64);
            dpen += __shfl_down(dpen, off, 64);
        }
        __shared__ double r_sq[BLOCK / 64], r_pen[BLOCK / 64];
        if (lane == 0) { r_sq[wave] = dsq; r_pen[wave] = dpen; }
        __syncthreads();
        if (threadIdx.x == 0) {
            double fsq = 0.0, fpen = 0.0;
            #pragma unroll
            for (int w = 0; w < BLOCK / 64; ++w) { fsq += r_sq[w]; fpen += r_pen[w]; }
            out[0] = (float)(fsq * invN + fpen * invB);
        }
    }
}

extern "C" void kernel_launch(void* const* d_in, const int* in_sizes, int n_in,
                              void* d_out, int out_size, void* d_ws, size_t ws_size,
                              hipStream_t stream) {
    const float* outs = (const float*)d_in[0];
    const float* tgts = (const float*)d_in[1];
    float* out = (float*)d_out;

    const long long n = (long long)in_sizes[0];        // B*3
    const long long n4 = n >> 2;
    const int nblocks = (int)((n4 + F4_PER_BLOCK - 1) / F4_PER_BLOCK); // 3072
    const double invN = 1.0 / (double)n;               // mse divisor = B*3
    const double invB = 3.0 / (double)n;               // penalty divisor = B

    unsigned long long* partials = (unsigned long long*)d_ws;
    unsigned* counter = (unsigned*)((char*)d_ws + (size_t)nblocks * 8);

    // counter must be 0 at kernel start every launch (capture-safe memset);
    // partials are fully overwritten.
    hipMemsetAsync(counter, 0, sizeof(unsigned), stream);

    bcmse_fused<<<nblocks, BLOCK, 0, stream>>>(outs, tgts, n, partials,
                                               counter, out, invN, invB);
}

// Round 5
// 133.258 us; speedup vs baseline: 1.0356x; 1.0356x over previous
//
#include <hip/hip_runtime.h>

// BCMSELoss: scalar = mean((out_full - tgt_full)^2) + sum(|floor(o_ang)|)/B
// cols 1,2 angular-wrapped, col 0 plain MSE. Memory-bound: 201 MB read.
//
// R1: grid-stride @16 VGPR -> latency-bound, 950 GB/s.
// R2: 3 f4-pairs/thread one-shot -> 4.5 TB/s.
// R3: 8 f4-pairs/thread, grid 3072 -> 5.2 TB/s (timed 38.8 us, 2 launches).
// R4 FAILED: acq_rel agent-scope atomic per block => buffer_wbl2 + L2
//    invalidate x3072 on non-coherent multi-XCD L2s -> 138 us. Lesson:
//    ordered agent-scope atomics are cache-maintenance ops on CDNA4.
// R5: fuse with RELAXED-only RMWs (execute at coherence point, no cache
//    ops): double atomicAdd accumulators + vmcnt(0) + relaxed counter;
//    last block RMW-reads the sums and writes out. One launch.

constexpr int BLOCK = 256;
constexpr int F4T = 8;                      // float4-pairs per thread
constexpr int F4_PER_BLOCK = BLOCK * F4T;   // 2048

__device__ inline void elem(float oo, float tt, bool ang, float& sq, float& pen) {
    const float fl = floorf(oo);
    const float ow = oo - fl;                       // mod(o, 1.0)
    const float shift = (tt < ow) ? 1.0f : -1.0f;
    const float ts = (fabsf(ow - tt) > 0.5f) ? (tt + shift) : tt;
    const float da = ow - ts;
    const float dl = oo - tt;
    const float d = ang ? da : dl;
    sq = fmaf(d, d, sq);
    pen += ang ? fabsf(fl) : 0.0f;
}

__device__ inline void proc4(const float4 o, const float4 t, int im,
                             float& sq, float& pen) {
    // element e = 4*i + j; 4 == 1 (mod 3) so e%3 == (i+j)%3; im = i%3
    elem(o.x, t.x, im != 0, sq, pen);
    const int c1 = (im == 2) ? 0 : im + 1;
    elem(o.y, t.y, c1 != 0, sq, pen);
    const int c2 = (c1 == 2) ? 0 : c1 + 1;
    elem(o.z, t.z, c2 != 0, sq, pen);
    const int c3 = (c2 == 2) ? 0 : c2 + 1;
    elem(o.w, t.w, c3 != 0, sq, pen);
}

__global__ __launch_bounds__(BLOCK) void bcmse_fused(
    const float* __restrict__ outs,
    const float* __restrict__ tgts,
    long long n,                       // total elements = B*3
    double* __restrict__ acc,          // acc[0]=sum_sq, acc[1]=sum_pen (zeroed)
    unsigned* __restrict__ counter,    // zeroed each launch
    float* __restrict__ out,
    double invN, double invB)
{
    const long long n4 = n >> 2;
    const long long base = (long long)blockIdx.x * F4_PER_BLOCK + threadIdx.x;

    const float4* __restrict__ o4 = reinterpret_cast<const float4*>(outs);
    const float4* __restrict__ t4 = reinterpret_cast<const float4*>(tgts);

    long long idx[F4T];
    bool g[F4T];
    #pragma unroll
    for (int k = 0; k < F4T; ++k) {
        const long long i = base + (long long)k * BLOCK;
        g[k] = i < n4;
        idx[k] = g[k] ? i : 0;
    }

    // issue all loads before any wait -> max MLP
    float4 ov[F4T], tv[F4T];
    #pragma unroll
    for (int k = 0; k < F4T; ++k) ov[k] = o4[idx[k]];
    #pragma unroll
    for (int k = 0; k < F4T; ++k) tv[k] = t4[idx[k]];

    // BLOCK=256, 256%3==1 -> i%3 advances by 1 per chunk
    int im = (int)(base % 3);

    float sq = 0.f, pen = 0.f;
    #pragma unroll
    for (int k = 0; k < F4T; ++k) {
        float s = 0.f, p = 0.f;
        proc4(ov[k], tv[k], im, s, p);
        if (g[k]) { sq += s; pen += p; }
        im = (im == 2) ? 0 : im + 1;
    }

    // scalar tail (n % 4 != 0) — never fires for n = 25165824
    if (blockIdx.x == 0 && threadIdx.x == 0) {
        for (long long e = n4 * 4; e < n; ++e) {
            elem(outs[e], tgts[e], (e % 3) != 0, sq, pen);
        }
    }

    // wave-64 reduce
    #pragma unroll
    for (int off = 32; off > 0; off >>= 1) {
        sq  += __shfl_down(sq,  off, 64);
        pen += __shfl_down(pen, off, 64);
    }

    __shared__ float s_sq[BLOCK / 64], s_pen[BLOCK / 64];
    const int lane = threadIdx.x & 63;
    const int wave = threadIdx.x >> 6;
    if (lane == 0) { s_sq[wave] = sq; s_pen[wave] = pen; }
    __syncthreads();

    if (threadIdx.x == 0) {
        float bsq = 0.f, bpen = 0.f;
        #pragma unroll
        for (int w = 0; w < BLOCK / 64; ++w) { bsq += s_sq[w]; bpen += s_pen[w]; }

        // Relaxed device-scope RMWs: execute at the coherence point, no
        // L2 writeback/invalidate (the R4 disaster).
        atomicAdd(&acc[0], (double)bsq);
        atomicAdd(&acc[1], (double)bpen);
        // Pure ack-wait (no cache maintenance): both adds are globally
        // visible at the coherence point before we bump the counter.
        asm volatile("s_waitcnt vmcnt(0)" ::: "memory");
        const unsigned prev = __hip_atomic_fetch_add(
            counter, 1u, __ATOMIC_RELAXED, __HIP_MEMORY_SCOPE_AGENT);

        if (prev == gridDim.x - 1) {
            // Last block: RMW-read the final sums (fetch_add(0) reads at the
            // coherence point; no acquire/invalidate needed).
            const double fsq = __hip_atomic_fetch_add(
                &acc[0], 0.0, __ATOMIC_RELAXED, __HIP_MEMORY_SCOPE_AGENT);
            const double fpen = __hip_atomic_fetch_add(
                &acc[1], 0.0, __ATOMIC_RELAXED, __HIP_MEMORY_SCOPE_AGENT);
            out[0] = (float)(fsq * invN + fpen * invB);
        }
    }
}

extern "C" void kernel_launch(void* const* d_in, const int* in_sizes, int n_in,
                              void* d_out, int out_size, void* d_ws, size_t ws_size,
                              hipStream_t stream) {
    const float* outs = (const float*)d_in[0];
    const float* tgts = (const float*)d_in[1];
    float* out = (float*)d_out;

    const long long n = (long long)in_sizes[0];        // B*3
    const long long n4 = n >> 2;
    const int nblocks = (int)((n4 + F4_PER_BLOCK - 1) / F4_PER_BLOCK); // 3072
    const double invN = 1.0 / (double)n;               // mse divisor = B*3
    const double invB = 3.0 / (double)n;               // penalty divisor = B

    double* acc = (double*)d_ws;                       // acc[0], acc[1]
    unsigned* counter = (unsigned*)((char*)d_ws + 16);

    // acc + counter must be zero at kernel start every launch (capture-safe)
    hipMemsetAsync(d_ws, 0, 24, stream);

    bcmse_fused<<<nblocks, BLOCK, 0, stream>>>(outs, tgts, n, acc,
                                               counter, out, invN, invB);
}

// Round 6
// 63.259 us; speedup vs baseline: 2.1815x; 2.1065x over previous
//
#include <hip/hip_runtime.h>

// BCMSELoss: scalar = mean((out_full - tgt_full)^2) + sum(|floor(o_ang)|)/B
// cols 1,2 angular-wrapped, col 0 plain MSE. Memory-bound: 201 MB read.
//
// R1: grid-stride @16 VGPR -> latency-bound, 950 GB/s.
// R2: 3 f4-pairs/thread one-shot -> 4.5 TB/s.
// R3: 8 f4-pairs/thread, grid 3072 -> timed 38.8 us (2 launches).
// R4 FAILED: acq_rel agent atomics => per-block L2 writeback+invalidate
//    (non-coherent XCD L2s) -> 138 us.
// R5 FAILED: atomicAdd(double) = CAS LOOP (no -munsafe-fp-atomics);
//    3072 blocks x 2 CAS on 2 addresses = retry storm tail (~77 us idle;
//    VALUBusy halved 14->7.3%, FETCH unchanged -> tail-serialized).
// R6: fused, contention-free epilogue: per-block partial via native
//    atomicExch u64 (swap_x2, distinct addrs, relaxed agent = coherence
//    point, no cache ops) + vmcnt(0) + ONE native u32 fetch_add/block;
//    last block RMW-reads partials (fetch_add 0) -> deterministic dbl sum.

constexpr int BLOCK = 256;
constexpr int F4T = 8;                      // float4-pairs per thread
constexpr int F4_PER_BLOCK = BLOCK * F4T;   // 2048

__device__ inline void elem(float oo, float tt, bool ang, float& sq, float& pen) {
    const float fl = floorf(oo);
    const float ow = oo - fl;                       // mod(o, 1.0)
    const float shift = (tt < ow) ? 1.0f : -1.0f;
    const float ts = (fabsf(ow - tt) > 0.5f) ? (tt + shift) : tt;
    const float da = ow - ts;
    const float dl = oo - tt;
    const float d = ang ? da : dl;
    sq = fmaf(d, d, sq);
    pen += ang ? fabsf(fl) : 0.0f;
}

__device__ inline void proc4(const float4 o, const float4 t, int im,
                             float& sq, float& pen) {
    // element e = 4*i + j; 4 == 1 (mod 3) so e%3 == (i+j)%3; im = i%3
    elem(o.x, t.x, im != 0, sq, pen);
    const int c1 = (im == 2) ? 0 : im + 1;
    elem(o.y, t.y, c1 != 0, sq, pen);
    const int c2 = (c1 == 2) ? 0 : c1 + 1;
    elem(o.z, t.z, c2 != 0, sq, pen);
    const int c3 = (c2 == 2) ? 0 : c2 + 1;
    elem(o.w, t.w, c3 != 0, sq, pen);
}

__global__ __launch_bounds__(BLOCK) void bcmse_fused(
    const float* __restrict__ outs,
    const float* __restrict__ tgts,
    long long n,                               // total elements = B*3
    unsigned long long* __restrict__ partials, // one packed float2 per block
    unsigned* __restrict__ counter,            // zeroed each launch
    float* __restrict__ out,
    double invN, double invB)
{
    const long long n4 = n >> 2;
    const long long base = (long long)blockIdx.x * F4_PER_BLOCK + threadIdx.x;

    const float4* __restrict__ o4 = reinterpret_cast<const float4*>(outs);
    const float4* __restrict__ t4 = reinterpret_cast<const float4*>(tgts);

    long long idx[F4T];
    bool g[F4T];
    #pragma unroll
    for (int k = 0; k < F4T; ++k) {
        const long long i = base + (long long)k * BLOCK;
        g[k] = i < n4;
        idx[k] = g[k] ? i : 0;
    }

    // issue all loads before any wait -> max MLP
    float4 ov[F4T], tv[F4T];
    #pragma unroll
    for (int k = 0; k < F4T; ++k) ov[k] = o4[idx[k]];
    #pragma unroll
    for (int k = 0; k < F4T; ++k) tv[k] = t4[idx[k]];

    // BLOCK=256, 256%3==1 -> i%3 advances by 1 per chunk
    int im = (int)(base % 3);

    float sq = 0.f, pen = 0.f;
    #pragma unroll
    for (int k = 0; k < F4T; ++k) {
        float s = 0.f, p = 0.f;
        proc4(ov[k], tv[k], im, s, p);
        if (g[k]) { sq += s; pen += p; }
        im = (im == 2) ? 0 : im + 1;
    }

    // scalar tail (n % 4 != 0) — never fires for n = 25165824
    if (blockIdx.x == 0 && threadIdx.x == 0) {
        for (long long e = n4 * 4; e < n; ++e) {
            elem(outs[e], tgts[e], (e % 3) != 0, sq, pen);
        }
    }

    // wave-64 reduce
    #pragma unroll
    for (int off = 32; off > 0; off >>= 1) {
        sq  += __shfl_down(sq,  off, 64);
        pen += __shfl_down(pen, off, 64);
    }

    __shared__ float s_sq[BLOCK / 64], s_pen[BLOCK / 64];
    __shared__ bool s_last;
    const int lane = threadIdx.x & 63;
    const int wave = threadIdx.x >> 6;
    if (lane == 0) { s_sq[wave] = sq; s_pen[wave] = pen; }
    __syncthreads();

    if (threadIdx.x == 0) {
        float bsq = 0.f, bpen = 0.f;
        #pragma unroll
        for (int w = 0; w < BLOCK / 64; ++w) { bsq += s_sq[w]; bpen += s_pen[w]; }

        union { float2 f; unsigned long long u; } pk;
        pk.f = make_float2(bsq, bpen);
        // Native swap_x2 to a DISTINCT address, relaxed agent scope:
        // executes at the coherence point (cross-XCD visible), no cache
        // maintenance, no retries, no contention.
        const unsigned long long old = __hip_atomic_exchange(
            &partials[blockIdx.x], pk.u,
            __ATOMIC_RELAXED, __HIP_MEMORY_SCOPE_AGENT);
        asm volatile("" :: "v"(old));          // keep the returning form
        // Pure ack-wait: swap has round-tripped the coherence point.
        asm volatile("s_waitcnt vmcnt(0)" ::: "memory");
        // ONE native u32 RMW per block (staggered arrivals -> hidden).
        const unsigned prev = __hip_atomic_fetch_add(
            counter, 1u, __ATOMIC_RELAXED, __HIP_MEMORY_SCOPE_AGENT);
        s_last = (prev == gridDim.x - 1);
    }
    __syncthreads();

    if (s_last) {
        // counter==grid => every swap reached the coherence point; RMW-reads
        // (fetch_add 0) observe them there. Fixed order -> deterministic.
        double dsq = 0.0, dpen = 0.0;
        const int nb = (int)gridDim.x;
        for (int k = threadIdx.x; k < nb; k += BLOCK) {
            union { float2 f; unsigned long long u; } pk;
            pk.u = __hip_atomic_fetch_add(
                &partials[k], 0ull,
                __ATOMIC_RELAXED, __HIP_MEMORY_SCOPE_AGENT);
            dsq  += (double)pk.f.x;
            dpen += (double)pk.f.y;
        }
        #pragma unroll
        for (int off = 32; off > 0; off >>= 1) {
            dsq  += __shfl_down(dsq,  off, 64);
            dpen += __shfl_down(dpen, off, 64);
        }
        __shared__ double r_sq[BLOCK / 64], r_pen[BLOCK / 64];
        if (lane == 0) { r_sq[wave] = dsq; r_pen[wave] = dpen; }
        __syncthreads();
        if (threadIdx.x == 0) {
            double fsq = 0.0, fpen = 0.0;
            #pragma unroll
            for (int w = 0; w < BLOCK / 64; ++w) { fsq += r_sq[w]; fpen += r_pen[w]; }
            out[0] = (float)(fsq * invN + fpen * invB);
        }
    }
}

extern "C" void kernel_launch(void* const* d_in, const int* in_sizes, int n_in,
                              void* d_out, int out_size, void* d_ws, size_t ws_size,
                              hipStream_t stream) {
    const float* outs = (const float*)d_in[0];
    const float* tgts = (const float*)d_in[1];
    float* out = (float*)d_out;

    const long long n = (long long)in_sizes[0];        // B*3
    const long long n4 = n >> 2;
    const int nblocks = (int)((n4 + F4_PER_BLOCK - 1) / F4_PER_BLOCK); // 3072
    const double invN = 1.0 / (double)n;               // mse divisor = B*3
    const double invB = 3.0 / (double)n;               // penalty divisor = B

    unsigned long long* partials = (unsigned long long*)d_ws;
    unsigned* counter = (unsigned*)((char*)d_ws + (size_t)nblocks * 8);

    // counter must be 0 at kernel start every launch; partials are all
    // swap-written before any read -> no need to clear them.
    hipMemsetAsync(counter, 0, sizeof(unsigned), stream);

    bcmse_fused<<<nblocks, BLOCK, 0, stream>>>(outs, tgts, n, partials,
                                               counter, out, invN, invB);
}

// Round 7
// 37.715 us; speedup vs baseline: 3.6591x; 1.6773x over previous
//
#include <hip/hip_runtime.h>

// BCMSELoss: scalar = mean((out_full - tgt_full)^2) + sum(|floor(o_ang)|)/B
// cols 1,2 angular-wrapped, col 0 plain MSE. Memory-bound: 201 MB read.
//
// R1: grid-stride @16 VGPR -> latency-bound, 950 GB/s.
// R2: 3 f4-pairs/thread one-shot -> 4.5 TB/s.
// R3: 8 f4-pairs/thread, grid 3072, 2 launches -> timed 38.8 us;
//     main kernel = 201MB/33.5us = 5.96 TB/s = 95% of 6.29 TB/s ceiling.
// R4 FAILED (138us): acq_rel agent atomics = per-block L2 wb+inv (XCD L2s
//     non-coherent).
// R5 FAILED (133us): atomicAdd(double) = CAS retry storm on 2 addresses.
// R6 FAILED (63us): even native-only relaxed epilogue (swap_x2 + counter)
//     costs ~15-25us. Lesson: ANY cross-block completion protocol on
//     8-XCD CDNA4 costs more than a 2nd graph launch (~5us). Un-fuse.
// R7: R3 + fast reduce: 1024 threads, unrolled INDEPENDENT guarded loads
//     (one memory round-trip instead of a 12-deep dependent chain).

constexpr int BLOCK = 256;
constexpr int F4T = 8;                      // float4-pairs per thread
constexpr int F4_PER_BLOCK = BLOCK * F4T;   // 2048
constexpr int RBLOCK = 1024;                // reduce-kernel threads
constexpr int RUNROLL = 3;                  // covers nblocks <= 3072

__device__ inline void elem(float oo, float tt, bool ang, float& sq, float& pen) {
    const float fl = floorf(oo);
    const float ow = oo - fl;                       // mod(o, 1.0)
    const float shift = (tt < ow) ? 1.0f : -1.0f;
    const float ts = (fabsf(ow - tt) > 0.5f) ? (tt + shift) : tt;
    const float da = ow - ts;
    const float dl = oo - tt;
    const float d = ang ? da : dl;
    sq = fmaf(d, d, sq);
    pen += ang ? fabsf(fl) : 0.0f;
}

__device__ inline void proc4(const float4 o, const float4 t, int im,
                             float& sq, float& pen) {
    // element e = 4*i + j; 4 == 1 (mod 3) so e%3 == (i+j)%3; im = i%3
    elem(o.x, t.x, im != 0, sq, pen);
    const int c1 = (im == 2) ? 0 : im + 1;
    elem(o.y, t.y, c1 != 0, sq, pen);
    const int c2 = (c1 == 2) ? 0 : c1 + 1;
    elem(o.z, t.z, c2 != 0, sq, pen);
    const int c3 = (c2 == 2) ? 0 : c2 + 1;
    elem(o.w, t.w, c3 != 0, sq, pen);
}

__global__ __launch_bounds__(BLOCK) void bcmse_partial(
    const float* __restrict__ outs,
    const float* __restrict__ tgts,
    long long n,                      // total elements = B*3
    float2* __restrict__ partials)    // one per block
{
    const long long n4 = n >> 2;
    const long long base = (long long)blockIdx.x * F4_PER_BLOCK + threadIdx.x;

    const float4* __restrict__ o4 = reinterpret_cast<const float4*>(outs);
    const float4* __restrict__ t4 = reinterpret_cast<const float4*>(tgts);

    long long idx[F4T];
    bool g[F4T];
    #pragma unroll
    for (int k = 0; k < F4T; ++k) {
        const long long i = base + (long long)k * BLOCK;
        g[k] = i < n4;
        idx[k] = g[k] ? i : 0;
    }

    // issue all loads before any wait -> max MLP
    float4 ov[F4T], tv[F4T];
    #pragma unroll
    for (int k = 0; k < F4T; ++k) ov[k] = o4[idx[k]];
    #pragma unroll
    for (int k = 0; k < F4T; ++k) tv[k] = t4[idx[k]];

    // BLOCK=256, 256%3==1 -> i%3 advances by 1 per chunk
    int im = (int)(base % 3);

    float sq = 0.f, pen = 0.f;
    #pragma unroll
    for (int k = 0; k < F4T; ++k) {
        float s = 0.f, p = 0.f;
        proc4(ov[k], tv[k], im, s, p);
        if (g[k]) { sq += s; pen += p; }
        im = (im == 2) ? 0 : im + 1;
    }

    // scalar tail (n % 4 != 0) — never fires for n = 25165824
    if (blockIdx.x == 0 && threadIdx.x == 0) {
        for (long long e = n4 * 4; e < n; ++e) {
            elem(outs[e], tgts[e], (e % 3) != 0, sq, pen);
        }
    }

    // wave-64 reduce
    #pragma unroll
    for (int off = 32; off > 0; off >>= 1) {
        sq  += __shfl_down(sq,  off, 64);
        pen += __shfl_down(pen, off, 64);
    }

    __shared__ float s_sq[BLOCK / 64], s_pen[BLOCK / 64];
    const int lane = threadIdx.x & 63;
    const int wave = threadIdx.x >> 6;
    if (lane == 0) { s_sq[wave] = sq; s_pen[wave] = pen; }
    __syncthreads();

    if (threadIdx.x == 0) {
        float bsq = 0.f, bpen = 0.f;
        #pragma unroll
        for (int w = 0; w < BLOCK / 64; ++w) { bsq += s_sq[w]; bpen += s_pen[w]; }
        partials[blockIdx.x] = make_float2(bsq, bpen);
    }
}

__global__ __launch_bounds__(RBLOCK) void bcmse_reduce(
    const float2* __restrict__ partials, int nblocks,
    float* __restrict__ out, double invN, double invB)
{
    double dsq = 0.0, dpen = 0.0;

    // Independent guarded loads, fully unrolled -> ONE memory round-trip
    // for nblocks <= RUNROLL*RBLOCK (3072). No dependent chain.
    #pragma unroll
    for (int r = 0; r < RUNROLL; ++r) {
        const int k = (int)threadIdx.x + r * RBLOCK;
        if (k < nblocks) {
            const float2 p = partials[k];
            dsq  += (double)p.x;
            dpen += (double)p.y;
        }
    }
    // generic tail for larger grids (never fires at nblocks==3072)
    for (int k = (int)threadIdx.x + RUNROLL * RBLOCK; k < nblocks; k += RBLOCK) {
        const float2 p = partials[k];
        dsq  += (double)p.x;
        dpen += (double)p.y;
    }

    #pragma unroll
    for (int off = 32; off > 0; off >>= 1) {
        dsq  += __shfl_down(dsq,  off, 64);
        dpen += __shfl_down(dpen, off, 64);
    }

    __shared__ double r_sq[RBLOCK / 64], r_pen[RBLOCK / 64];
    const int lane = threadIdx.x & 63;
    const int wave = threadIdx.x >> 6;
    if (lane == 0) { r_sq[wave] = dsq; r_pen[wave] = dpen; }
    __syncthreads();

    if (threadIdx.x == 0) {
        double fsq = 0.0, fpen = 0.0;
        #pragma unroll
        for (int w = 0; w < RBLOCK / 64; ++w) { fsq += r_sq[w]; fpen += r_pen[w]; }
        out[0] = (float)(fsq * invN + fpen * invB);
    }
}

extern "C" void kernel_launch(void* const* d_in, const int* in_sizes, int n_in,
                              void* d_out, int out_size, void* d_ws, size_t ws_size,
                              hipStream_t stream) {
    const float* outs = (const float*)d_in[0];
    const float* tgts = (const float*)d_in[1];
    float* out = (float*)d_out;
    float2* partials = (float2*)d_ws;

    const long long n = (long long)in_sizes[0];        // B*3
    const long long n4 = n >> 2;
    const int nblocks = (int)((n4 + F4_PER_BLOCK - 1) / F4_PER_BLOCK); // 3072
    const double invN = 1.0 / (double)n;               // mse divisor = B*3
    const double invB = 3.0 / (double)n;               // penalty divisor = B

    // partials[0..nblocks) fully overwritten each launch -> no memset needed
    bcmse_partial<<<nblocks, BLOCK, 0, stream>>>(outs, tgts, n, partials);
    bcmse_reduce<<<1, RBLOCK, 0, stream>>>(partials, nblocks, out, invN, invB);
}